// Round 6
// baseline (160.520 us; speedup 1.0000x reference)
//
#include <hip/hip_runtime.h>
#include <hip/hip_bf16.h>

// Problem constants
#define Bv 4
#define Sv 4096
#define Dv 1024
#define Hv 16
#define Ov 64
#define NCv 64
#define BHv 64

typedef __attribute__((ext_vector_type(8))) short bf16x8;
typedef __attribute__((ext_vector_type(4))) unsigned short u16x4;
typedef __attribute__((ext_vector_type(8))) unsigned short u16x8;
typedef __attribute__((ext_vector_type(4))) float f32x4;
#define MFMA(a, b, c) __builtin_amdgcn_mfma_f32_16x16x32_bf16(a, b, c, 0, 0, 0)

__device__ __forceinline__ unsigned short f2bs(float f) {
  union { __hip_bfloat16 h; unsigned short u; } v;
  v.h = __float2bfloat16(f);
  return v.u;
}
__device__ __forceinline__ float b2f(unsigned short u) {
  union { unsigned u; float f; } v; v.u = ((unsigned)u) << 16; return v.f;
}
__device__ __forceinline__ float elu1(float a) {
  return a > 0.f ? a + 1.f : __expf(a);
}
__device__ __forceinline__ f32x4 zero4() {
  f32x4 v = {0.f, 0.f, 0.f, 0.f}; return v;
}
__device__ __forceinline__ bf16x8 pack8(float4 a, float4 b) {
  union { u16x8 u; bf16x8 h; } r;
  r.u[0] = f2bs(a.x); r.u[1] = f2bs(a.y); r.u[2] = f2bs(a.z); r.u[3] = f2bs(a.w);
  r.u[4] = f2bs(b.x); r.u[5] = f2bs(b.y); r.u[6] = f2bs(b.z); r.u[7] = f2bs(b.w);
  return r.h;
}

// ---------------------------------------------------------------------------
// K0 prep: Wq/Wk/Wv [h][d][o] -> bf16 [h][o][d]; Wp [d][o2] -> bf16 [o2][d]
// ---------------------------------------------------------------------------
__global__ __launch_bounds__(256) void k_prep_w(
    const float* __restrict__ Wq, const float* __restrict__ Wk,
    const float* __restrict__ Wv, const float* __restrict__ Wp,
    unsigned short* __restrict__ wqT, unsigned short* __restrict__ wkT,
    unsigned short* __restrict__ wvT, unsigned short* __restrict__ wpT)
{
  const int blk = blockIdx.x, tid = threadIdx.x;
  if (blk < 16) {
    int h = blk;
    for (int j = tid; j < 4096; j += 256) {       // j = o*64 + d (output idx)
      int o = j >> 6, d = j & 63;
      int src = h * 4096 + d * 64 + o;
      wqT[h * 4096 + j] = f2bs(Wq[src]);
      wkT[h * 4096 + j] = f2bs(Wk[src]);
      wvT[h * 4096 + j] = f2bs(Wv[src]);
    }
  } else {
    int b2 = blk - 16;
#pragma unroll
    for (int k = 0; k < 4; ++k) {
      int j = b2 * 1024 + tid + k * 256;          // j = o2*1024 + d
      int o = j >> 10, d = j & 1023;
      wpT[j] = f2bs(Wp[d * 64 + o]);
    }
  }
}

// ---------------------------------------------------------------------------
// K1: per (bh,chunk): K=elu1(x Wk), V=x Wv
//   publishes: kg [s][e] bf16 (direct frag stores), vg [o][t] bf16,
//              mir [o][e] = (K^T V)^T bf16, zmir [e] f32
// ---------------------------------------------------------------------------
__global__ __launch_bounds__(256) void k_chunk_state(
    const float* __restrict__ x, const unsigned short* __restrict__ wkT,
    const unsigned short* __restrict__ wvT, unsigned short* __restrict__ mir,
    float* __restrict__ zmir, unsigned short* __restrict__ krow_g,
    unsigned short* __restrict__ vtg)
{
  __shared__ __align__(16) unsigned short kT[64][72];     // K^T[e][t]
  __shared__ __align__(16) unsigned short vT[64][72];     // V^T[o][t]
  __shared__ float zpart[4][64];

  const int tid = threadIdx.x, blk = blockIdx.x;
  const int c = blk & 63, bh = blk >> 6, h = bh & 15, b = bh >> 4;
  const int lane = tid & 63, w = tid >> 6;
  const int ll = lane & 15, hl = lane >> 4;

  // x fragment (f32 -> bf16 in-register)
  const float* xr = x + ((size_t)(b * Sv + c * 64 + w * 16 + ll)) * 1024 + h * 64;
  float4 f0 = *(const float4*)(xr + hl * 8);
  float4 f1 = *(const float4*)(xr + hl * 8 + 4);
  float4 f2 = *(const float4*)(xr + 32 + hl * 8);
  float4 f3 = *(const float4*)(xr + 32 + hl * 8 + 4);
  const bf16x8 xa0 = pack8(f0, f1);
  const bf16x8 xa1 = pack8(f2, f3);

  unsigned short* kg = krow_g + (size_t)blk * 4096;

  // K = elu1(x Wk) -> kT LDS + kg global + zpart
  const unsigned short* wk = wkT + h * 4096;
#pragma unroll
  for (int ct = 0; ct < 4; ++ct) {
    bf16x8 b0 = *(const bf16x8*)(wk + (ct * 16 + ll) * 64 + hl * 8);
    bf16x8 b1 = *(const bf16x8*)(wk + (ct * 16 + ll) * 64 + 32 + hl * 8);
    f32x4 a = zero4(); a = MFMA(xa0, b0, a); a = MFMA(xa1, b1, a);
    u16x4 p; float part = 0.f;
#pragma unroll
    for (int r = 0; r < 4; ++r) {
      float kv = elu1(a[r]); part += kv;
      p[r] = f2bs(kv);
      kg[(w * 16 + hl * 4 + r) * 64 + ct * 16 + ll] = p[r];
    }
    *(u16x4*)&kT[ct * 16 + ll][w * 16 + hl * 4] = p;
    part += __shfl_xor(part, 16);
    part += __shfl_xor(part, 32);
    if (hl == 0) zpart[w][ct * 16 + ll] = part;
  }
  // V = x Wv -> vT[o][t]
  const unsigned short* wv = wvT + h * 4096;
#pragma unroll
  for (int ct = 0; ct < 4; ++ct) {
    bf16x8 b0 = *(const bf16x8*)(wv + (ct * 16 + ll) * 64 + hl * 8);
    bf16x8 b1 = *(const bf16x8*)(wv + (ct * 16 + ll) * 64 + 32 + hl * 8);
    f32x4 a = zero4(); a = MFMA(xa0, b0, a); a = MFMA(xa1, b1, a);
    u16x4 p;
#pragma unroll
    for (int r = 0; r < 4; ++r) p[r] = f2bs(a[r]);
    *(u16x4*)&vT[ct * 16 + ll][w * 16 + hl * 4] = p;
  }
  __syncthreads();

  // KtV: C[e][o]; write transposed [o][e] to mir
  const bf16x8 ka0 = *(const bf16x8*)&kT[w * 16 + ll][hl * 8];
  const bf16x8 ka1 = *(const bf16x8*)&kT[w * 16 + ll][32 + hl * 8];
  unsigned short* mp = mir + (size_t)blk * 4096;
#pragma unroll
  for (int ct = 0; ct < 4; ++ct) {
    bf16x8 v0 = *(const bf16x8*)&vT[ct * 16 + ll][hl * 8];
    bf16x8 v1 = *(const bf16x8*)&vT[ct * 16 + ll][32 + hl * 8];
    f32x4 s = zero4(); s = MFMA(ka0, v0, s); s = MFMA(ka1, v1, s);
    u16x4 p;
#pragma unroll
    for (int r = 0; r < 4; ++r) p[r] = f2bs(s[r]);
    *(u16x4*)&mp[(ct * 16 + ll) * 64 + w * 16 + hl * 4] = p;
  }
  // coalesced publish of vT
  unsigned short* vg = vtg + (size_t)blk * 4096;
#pragma unroll
  for (int it = 0; it < 2; ++it) {
    int j = tid * 8 + it * 2048;
    int r = j >> 6, col = j & 63;
    *(uint4*)&vg[j] = *(const uint4*)&vT[r][col];
  }
  if (tid < 64)
    zmir[(size_t)blk * 64 + tid] =
        zpart[0][tid] + zpart[1][tid] + zpart[2][tid] + zpart[3][tid];
}

// ---------------------------------------------------------------------------
// K2: exclusive prefix over chunks — loads up-front, register scan, stores.
// ---------------------------------------------------------------------------
__global__ __launch_bounds__(256) void k_prefix(
    unsigned short* __restrict__ mir, float* __restrict__ zmir)
{
  const int bh = blockIdx.x / 17, g = blockIdx.x % 17;
  const int tid = threadIdx.x;
  if (g < 16) {
    size_t base = (size_t)bh * 64 * 4096 + g * 256 + tid;
    unsigned short v[64];
#pragma unroll
    for (int cc = 0; cc < 64; ++cc) v[cc] = mir[base + (size_t)cc * 4096];
    float carry = 0.f;
#pragma unroll
    for (int cc = 0; cc < 64; ++cc) {
      float f = b2f(v[cc]);
      v[cc] = f2bs(carry);
      carry += f;
    }
#pragma unroll
    for (int cc = 0; cc < 64; ++cc) mir[base + (size_t)cc * 4096] = v[cc];
  } else if (tid < 64) {
    size_t base = (size_t)bh * 64 * 64 + tid;
    float v[64];
#pragma unroll
    for (int cc = 0; cc < 64; ++cc) v[cc] = zmir[base + (size_t)cc * 64];
    float carry = 0.f;
#pragma unroll
    for (int cc = 0; cc < 64; ++cc) {
      float f = v[cc];
      v[cc] = carry;
      carry += f;
    }
#pragma unroll
    for (int cc = 0; cc < 64; ++cc) zmir[base + (size_t)cc * 64] = v[cc];
  }
}

// ---------------------------------------------------------------------------
// K3: per (b,chunk,head-pair): TWO heads fully unrolled + phase-interleaved
// (independent chains, private LDS buffers) -> ILP hides L3/LDS/MFMA latency.
//   y_h = (Q Sprev + tril(Q K^T) V) / (q.zprev + rowsum + eps)
//   oacc += y_h @ Wp_h      -> partial[g] (bf16)
// ---------------------------------------------------------------------------
__global__ __launch_bounds__(256) void k_out(
    const float* __restrict__ x, const unsigned short* __restrict__ wqT,
    const unsigned short* __restrict__ krow_g, const unsigned short* __restrict__ vtg,
    const unsigned short* __restrict__ mir, const float* __restrict__ zmir,
    const unsigned short* __restrict__ wpT, unsigned short* __restrict__ partial)
{
  __shared__ __align__(16) unsigned short ts0[64][72];
  __shared__ __align__(16) unsigned short ts1[64][72];

  const int tid = threadIdx.x, bid = blockIdx.x;
  const int g = bid & 7, c = (bid >> 3) & 63, b = bid >> 9;
  const int lane = tid & 63, w = tid >> 6;
  const int ll = lane & 15, hl = lane >> 4;

  const int h0 = g * 2, h1 = g * 2 + 1;
  const size_t sblk0 = (size_t)((b * 16 + h0) * 64 + c);
  const size_t sblk1 = (size_t)((b * 16 + h1) * 64 + c);

  // ---- phase 0: x fragments for BOTH heads ----
  const float* xr = x + ((size_t)(b * Sv + c * 64 + w * 16 + ll)) * 1024;
  float4 a0_0 = *(const float4*)(xr + h0 * 64 + hl * 8);
  float4 a1_0 = *(const float4*)(xr + h0 * 64 + hl * 8 + 4);
  float4 a2_0 = *(const float4*)(xr + h0 * 64 + 32 + hl * 8);
  float4 a3_0 = *(const float4*)(xr + h0 * 64 + 32 + hl * 8 + 4);
  float4 a0_1 = *(const float4*)(xr + h1 * 64 + hl * 8);
  float4 a1_1 = *(const float4*)(xr + h1 * 64 + hl * 8 + 4);
  float4 a2_1 = *(const float4*)(xr + h1 * 64 + 32 + hl * 8);
  float4 a3_1 = *(const float4*)(xr + h1 * 64 + 32 + hl * 8 + 4);
  const bf16x8 xa0_0 = pack8(a0_0, a1_0), xa1_0 = pack8(a2_0, a3_0);
  const bf16x8 xa0_1 = pack8(a0_1, a1_1), xa1_1 = pack8(a2_1, a3_1);

  // ---- phase 1: Q projections (both) ----
  const unsigned short* wq0 = wqT + h0 * 4096;
  const unsigned short* wq1 = wqT + h1 * 4096;
  f32x4 qacc0[4], qacc1[4];
#pragma unroll
  for (int ct = 0; ct < 4; ++ct) {
    bf16x8 b00 = *(const bf16x8*)(wq0 + (ct * 16 + ll) * 64 + hl * 8);
    bf16x8 b01 = *(const bf16x8*)(wq0 + (ct * 16 + ll) * 64 + 32 + hl * 8);
    f32x4 q0 = zero4(); q0 = MFMA(xa0_0, b00, q0); q0 = MFMA(xa1_0, b01, q0);
    qacc0[ct] = q0;
    bf16x8 b10 = *(const bf16x8*)(wq1 + (ct * 16 + ll) * 64 + hl * 8);
    bf16x8 b11 = *(const bf16x8*)(wq1 + (ct * 16 + ll) * 64 + 32 + hl * 8);
    f32x4 q1 = zero4(); q1 = MFMA(xa0_1, b10, q1); q1 = MFMA(xa1_1, b11, q1);
    qacc1[ct] = q1;
  }

  // ---- phase 2: elu + den0 + Q transposes (both) ----
  const float* zp0 = zmir + sblk0 * 64;
  const float* zp1 = zmir + sblk1 * 64;
  float den00[4] = {0.f, 0.f, 0.f, 0.f};
  float den01[4] = {0.f, 0.f, 0.f, 0.f};
#pragma unroll
  for (int ct = 0; ct < 4; ++ct) {
    float zv0 = zp0[ct * 16 + ll];
    float zv1 = zp1[ct * 16 + ll];
#pragma unroll
    for (int r = 0; r < 4; ++r) {
      float q0 = elu1(qacc0[ct][r]);
      den00[r] += q0 * zv0;
      ts0[w * 16 + hl * 4 + r][ct * 16 + ll] = f2bs(q0);
      float q1 = elu1(qacc1[ct][r]);
      den01[r] += q1 * zv1;
      ts1[w * 16 + hl * 4 + r][ct * 16 + ll] = f2bs(q1);
    }
  }
#pragma unroll
  for (int m = 1; m <= 8; m <<= 1)
#pragma unroll
    for (int r = 0; r < 4; ++r) {
      den00[r] += __shfl_xor(den00[r], m);
      den01[r] += __shfl_xor(den01[r], m);
    }

  const bf16x8 qa0_0 = *(const bf16x8*)&ts0[w * 16 + ll][hl * 8];
  const bf16x8 qa1_0 = *(const bf16x8*)&ts0[w * 16 + ll][32 + hl * 8];
  const bf16x8 qa0_1 = *(const bf16x8*)&ts1[w * 16 + ll][hl * 8];
  const bf16x8 qa1_1 = *(const bf16x8*)&ts1[w * 16 + ll][32 + hl * 8];

  // ---- phase 3: A = tril(Q K^T) (both) ----
  const unsigned short* kg0 = krow_g + sblk0 * 4096;
  const unsigned short* kg1 = krow_g + sblk1 * 4096;
  f32x4 aacc0[4], aacc1[4];
#pragma unroll
  for (int ct = 0; ct < 4; ++ct) {
    if (ct <= w) {   // wave-uniform
      bf16x8 b00 = *(const bf16x8*)(kg0 + (ct * 16 + ll) * 64 + hl * 8);
      bf16x8 b01 = *(const bf16x8*)(kg0 + (ct * 16 + ll) * 64 + 32 + hl * 8);
      f32x4 s0 = zero4(); s0 = MFMA(qa0_0, b00, s0); s0 = MFMA(qa1_0, b01, s0);
      bf16x8 b10 = *(const bf16x8*)(kg1 + (ct * 16 + ll) * 64 + hl * 8);
      bf16x8 b11 = *(const bf16x8*)(kg1 + (ct * 16 + ll) * 64 + 32 + hl * 8);
      f32x4 s1 = zero4(); s1 = MFMA(qa0_1, b10, s1); s1 = MFMA(qa1_1, b11, s1);
      if (ct == w) {  // causal mask on diagonal tile (static indices)
#pragma unroll
        for (int r = 0; r < 4; ++r)
          if (ll > hl * 4 + r) { s0[r] = 0.f; s1[r] = 0.f; }
      }
      aacc0[ct] = s0; aacc1[ct] = s1;
    } else {
      aacc0[ct] = zero4(); aacc1[ct] = zero4();
    }
  }
  // rowsums
  float denA0[4], denA1[4];
#pragma unroll
  for (int r = 0; r < 4; ++r) {
    denA0[r] = aacc0[0][r] + aacc0[1][r] + aacc0[2][r] + aacc0[3][r];
    denA1[r] = aacc1[0][r] + aacc1[1][r] + aacc1[2][r] + aacc1[3][r];
  }
#pragma unroll
  for (int m = 1; m <= 8; m <<= 1)
#pragma unroll
    for (int r = 0; r < 4; ++r) {
      denA0[r] += __shfl_xor(denA0[r], m);
      denA1[r] += __shfl_xor(denA1[r], m);
    }
  // A transposes (buffer reuse; in-order DS pipe per wave -> safe)
#pragma unroll
  for (int ct = 0; ct < 4; ++ct)
#pragma unroll
    for (int r = 0; r < 4; ++r) {
      ts0[w * 16 + hl * 4 + r][ct * 16 + ll] = f2bs(aacc0[ct][r]);
      ts1[w * 16 + hl * 4 + r][ct * 16 + ll] = f2bs(aacc1[ct][r]);
    }
  const bf16x8 aa0_0 = *(const bf16x8*)&ts0[w * 16 + ll][hl * 8];
  const bf16x8 aa1_0 = *(const bf16x8*)&ts0[w * 16 + ll][32 + hl * 8];
  const bf16x8 aa0_1 = *(const bf16x8*)&ts1[w * 16 + ll][hl * 8];
  const bf16x8 aa1_1 = *(const bf16x8*)&ts1[w * 16 + ll][32 + hl * 8];

  // ---- phase 4: num = Q Sprev + A V (both) ----
  const unsigned short* sp0 = mir + sblk0 * 4096;
  const unsigned short* sp1 = mir + sblk1 * 4096;
  const unsigned short* vg0 = vtg + sblk0 * 4096;
  const unsigned short* vg1 = vtg + sblk1 * 4096;
  f32x4 nacc0[4], nacc1[4];
#pragma unroll
  for (int ct = 0; ct < 4; ++ct) {
    bf16x8 s00 = *(const bf16x8*)(sp0 + (ct * 16 + ll) * 64 + hl * 8);
    bf16x8 s01 = *(const bf16x8*)(sp0 + (ct * 16 + ll) * 64 + 32 + hl * 8);
    f32x4 n0 = zero4(); n0 = MFMA(qa0_0, s00, n0); n0 = MFMA(qa1_0, s01, n0);
    bf16x8 s10 = *(const bf16x8*)(sp1 + (ct * 16 + ll) * 64 + hl * 8);
    bf16x8 s11 = *(const bf16x8*)(sp1 + (ct * 16 + ll) * 64 + 32 + hl * 8);
    f32x4 n1 = zero4(); n1 = MFMA(qa0_1, s10, n1); n1 = MFMA(qa1_1, s11, n1);
    bf16x8 v00 = *(const bf16x8*)(vg0 + (ct * 16 + ll) * 64 + hl * 8);
    n0 = MFMA(aa0_0, v00, n0);
    bf16x8 v10 = *(const bf16x8*)(vg1 + (ct * 16 + ll) * 64 + hl * 8);
    n1 = MFMA(aa0_1, v10, n1);
    if (w >= 2) {    // rows t>=32: s in [32,64) can be nonzero
      bf16x8 v01 = *(const bf16x8*)(vg0 + (ct * 16 + ll) * 64 + 32 + hl * 8);
      n0 = MFMA(aa1_0, v01, n0);
      bf16x8 v11 = *(const bf16x8*)(vg1 + (ct * 16 + ll) * 64 + 32 + hl * 8);
      n1 = MFMA(aa1_1, v11, n1);
    }
    nacc0[ct] = n0; nacc1[ct] = n1;
  }

  // ---- phase 5: divide + y transposes (both) ----
  float inv0[4], inv1[4];
#pragma unroll
  for (int r = 0; r < 4; ++r) {
    inv0[r] = 1.f / (den00[r] + denA0[r] + 1e-6f);
    inv1[r] = 1.f / (den01[r] + denA1[r] + 1e-6f);
  }
#pragma unroll
  for (int ct = 0; ct < 4; ++ct)
#pragma unroll
    for (int r = 0; r < 4; ++r) {
      ts0[w * 16 + hl * 4 + r][ct * 16 + ll] = f2bs(nacc0[ct][r] * inv0[r]);
      ts1[w * 16 + hl * 4 + r][ct * 16 + ll] = f2bs(nacc1[ct][r] * inv1[r]);
    }
  const bf16x8 ya0_0 = *(const bf16x8*)&ts0[w * 16 + ll][hl * 8];
  const bf16x8 ya1_0 = *(const bf16x8*)&ts0[w * 16 + ll][32 + hl * 8];
  const bf16x8 ya0_1 = *(const bf16x8*)&ts1[w * 16 + ll][hl * 8];
  const bf16x8 ya1_1 = *(const bf16x8*)&ts1[w * 16 + ll][32 + hl * 8];

  // ---- phase 6: oacc = y0 @ Wp_h0 + y1 @ Wp_h1 ----
  f32x4 oacc[4];
#pragma unroll
  for (int ct = 0; ct < 4; ++ct) {
    const unsigned short* wpr = wpT + (size_t)(ct * 16 + ll) * 1024;
    bf16x8 w00 = *(const bf16x8*)(wpr + h0 * 64 + hl * 8);
    bf16x8 w01 = *(const bf16x8*)(wpr + h0 * 64 + 32 + hl * 8);
    f32x4 o = zero4();
    o = MFMA(ya0_0, w00, o); o = MFMA(ya1_0, w01, o);
    bf16x8 w10 = *(const bf16x8*)(wpr + h1 * 64 + hl * 8);
    bf16x8 w11 = *(const bf16x8*)(wpr + h1 * 64 + 32 + hl * 8);
    o = MFMA(ya0_1, w10, o); o = MFMA(ya1_1, w11, o);
    oacc[ct] = o;
  }

  // coalesced bf16 partial store via ts0 (wave-private rows; no barrier)
#pragma unroll
  for (int ct = 0; ct < 4; ++ct)
#pragma unroll
    for (int r = 0; r < 4; ++r)
      ts0[w * 16 + hl * 4 + r][ct * 16 + ll] = f2bs(oacc[ct][r]);
  unsigned short* pp = partial + (size_t)g * 1048576 +
                       ((size_t)(b * Sv + c * 64)) * 64;
  {
    int r_ = tid >> 2, c_ = (tid & 3) * 16;
    uint4 q0 = *(const uint4*)&ts0[r_][c_];
    uint4 q1 = *(const uint4*)&ts0[r_][c_ + 8];
    *(uint4*)&pp[r_ * 64 + c_] = q0;
    *(uint4*)&pp[r_ * 64 + c_ + 8] = q1;
  }
}

// ---------------------------------------------------------------------------
// K4: out = sum_g partial[g]  (bf16 -> f32)
// ---------------------------------------------------------------------------
__global__ __launch_bounds__(256) void k_add(
    const unsigned short* __restrict__ partial, float* __restrict__ out)
{
  const int idx = (blockIdx.x * 256 + threadIdx.x) * 8;
  float acc[8] = {0.f, 0.f, 0.f, 0.f, 0.f, 0.f, 0.f, 0.f};
#pragma unroll
  for (int g = 0; g < 8; ++g) {
    u16x8 p = *(const u16x8*)(partial + (size_t)g * 1048576 + idx);
#pragma unroll
    for (int j = 0; j < 8; ++j) acc[j] += b2f(p[j]);
  }
  float4 r0 = {acc[0], acc[1], acc[2], acc[3]};
  float4 r1 = {acc[4], acc[5], acc[6], acc[7]};
  *(float4*)(out + idx) = r0;
  *(float4*)(out + idx + 4) = r1;
}

// ---------------------------------------------------------------------------
extern "C" void kernel_launch(void* const* d_in, const int* in_sizes, int n_in,
                              void* d_out, int out_size, void* d_ws, size_t ws_size,
                              hipStream_t stream)
{
  const float* x  = (const float*)d_in[0];
  const float* Wq = (const float*)d_in[1];
  const float* Wk = (const float*)d_in[2];
  const float* Wv = (const float*)d_in[3];
  const float* Wp = (const float*)d_in[4];
  float* out = (float*)d_out;

  unsigned short* mir = (unsigned short*)d_ws;
  float* zmir = (float*)((char*)d_ws + 33554432);
  unsigned short* krow_g = (unsigned short*)((char*)d_ws + 34603008);
  unsigned short* vtg = krow_g + 16777216;
  unsigned short* wqT = vtg + 16777216;
  unsigned short* wkT = wqT + 65536;
  unsigned short* wvT = wkT + 65536;
  unsigned short* wpT = wvT + 65536;
  unsigned short* partial = wpT + 65536;

  hipLaunchKernelGGL(k_prep_w, dim3(80), dim3(256), 0, stream,
                     Wq, Wk, Wv, Wp, wqT, wkT, wvT, wpT);
  hipLaunchKernelGGL(k_chunk_state, dim3(BHv * NCv), dim3(256), 0, stream,
                     x, wkT, wvT, mir, zmir, krow_g, vtg);
  hipLaunchKernelGGL(k_prefix, dim3(BHv * 17), dim3(256), 0, stream, mir, zmir);
  hipLaunchKernelGGL(k_out, dim3(Bv * NCv * 8), dim3(256), 0, stream,
                     x, wqT, krow_g, vtg, mir, zmir, wpT, partial);
  hipLaunchKernelGGL(k_add, dim3(512), dim3(256), 0, stream, partial, out);
}

// Round 8
// 154.252 us; speedup vs baseline: 1.0406x; 1.0406x over previous
//
#include <hip/hip_runtime.h>
#include <hip/hip_bf16.h>

// Problem constants
#define Bv 4
#define Sv 4096
#define Dv 1024
#define Hv 16
#define Ov 64
#define NCv 64
#define BHv 64

typedef __attribute__((ext_vector_type(8))) short bf16x8;
typedef __attribute__((ext_vector_type(4))) unsigned short u16x4;
typedef __attribute__((ext_vector_type(8))) unsigned short u16x8;
typedef __attribute__((ext_vector_type(4))) float f32x4;
#define MFMA(a, b, c) __builtin_amdgcn_mfma_f32_16x16x32_bf16(a, b, c, 0, 0, 0)

__device__ __forceinline__ unsigned short f2bs(float f) {
  union { __hip_bfloat16 h; unsigned short u; } v;
  v.h = __float2bfloat16(f);
  return v.u;
}
__device__ __forceinline__ float b2f(unsigned short u) {
  union { unsigned u; float f; } v; v.u = ((unsigned)u) << 16; return v.f;
}
__device__ __forceinline__ float elu1(float a) {
  return a > 0.f ? a + 1.f : __expf(a);
}
__device__ __forceinline__ f32x4 zero4() {
  f32x4 v = {0.f, 0.f, 0.f, 0.f}; return v;
}
__device__ __forceinline__ bf16x8 pack8(float4 a, float4 b) {
  union { u16x8 u; bf16x8 h; } r;
  r.u[0] = f2bs(a.x); r.u[1] = f2bs(a.y); r.u[2] = f2bs(a.z); r.u[3] = f2bs(a.w);
  r.u[4] = f2bs(b.x); r.u[5] = f2bs(b.y); r.u[6] = f2bs(b.z); r.u[7] = f2bs(b.w);
  return r.h;
}

// ---------------------------------------------------------------------------
// K0 prep: Wq/Wk/Wv [h][d][o] -> bf16 [h][o][d]; Wp [d][o2] -> bf16 [o2][d]
// ---------------------------------------------------------------------------
__global__ __launch_bounds__(256) void k_prep_w(
    const float* __restrict__ Wq, const float* __restrict__ Wk,
    const float* __restrict__ Wv, const float* __restrict__ Wp,
    unsigned short* __restrict__ wqT, unsigned short* __restrict__ wkT,
    unsigned short* __restrict__ wvT, unsigned short* __restrict__ wpT)
{
  const int blk = blockIdx.x, tid = threadIdx.x;
  if (blk < 16) {
    int h = blk;
    for (int j = tid; j < 4096; j += 256) {       // j = o*64 + d (output idx)
      int o = j >> 6, d = j & 63;
      int src = h * 4096 + d * 64 + o;
      wqT[h * 4096 + j] = f2bs(Wq[src]);
      wkT[h * 4096 + j] = f2bs(Wk[src]);
      wvT[h * 4096 + j] = f2bs(Wv[src]);
    }
  } else {
    int b2 = blk - 16;
#pragma unroll
    for (int k = 0; k < 4; ++k) {
      int j = b2 * 1024 + tid + k * 256;          // j = o2*1024 + d
      int o = j >> 10, d = j & 1023;
      wpT[j] = f2bs(Wp[d * 64 + o]);
    }
  }
}

// ---------------------------------------------------------------------------
// K1: per (bh,chunk): Q=elu1(x Wq), K=elu1(x Wk), V=x Wv   (x read ONCE here)
//   publishes: qg [t][e] bf16, kg [s][e] bf16, vg [o][t] bf16,
//              mir [o][e] = (K^T V)^T bf16, zmir [e] bf16
// ---------------------------------------------------------------------------
__global__ __launch_bounds__(256) void k_chunk_state(
    const float* __restrict__ x, const unsigned short* __restrict__ wqT,
    const unsigned short* __restrict__ wkT, const unsigned short* __restrict__ wvT,
    unsigned short* __restrict__ mir, unsigned short* __restrict__ zmir,
    unsigned short* __restrict__ qg, unsigned short* __restrict__ kg_g,
    unsigned short* __restrict__ vtg)
{
  __shared__ __align__(16) unsigned short kT[64][72];     // K^T[e][t]
  __shared__ __align__(16) unsigned short vT[64][72];     // V^T[o][t]
  __shared__ float zpart[4][64];

  const int tid = threadIdx.x, blk = blockIdx.x;
  const int c = blk & 63, bh = blk >> 6, h = bh & 15, b = bh >> 4;
  const int lane = tid & 63, w = tid >> 6;
  const int ll = lane & 15, hl = lane >> 4;

  // x fragment (f32 -> bf16 in-register); the ONLY x read in the pipeline
  const float* xr = x + ((size_t)(b * Sv + c * 64 + w * 16 + ll)) * 1024 + h * 64;
  float4 f0 = *(const float4*)(xr + hl * 8);
  float4 f1 = *(const float4*)(xr + hl * 8 + 4);
  float4 f2 = *(const float4*)(xr + 32 + hl * 8);
  float4 f3 = *(const float4*)(xr + 32 + hl * 8 + 4);
  const bf16x8 xa0 = pack8(f0, f1);
  const bf16x8 xa1 = pack8(f2, f3);

  // Q = elu1(x Wq) -> qg rows [t][e]
  const unsigned short* wq = wqT + h * 4096;
  unsigned short* qp = qg + (size_t)blk * 4096;
#pragma unroll
  for (int ct = 0; ct < 4; ++ct) {
    bf16x8 b0 = *(const bf16x8*)(wq + (ct * 16 + ll) * 64 + hl * 8);
    bf16x8 b1 = *(const bf16x8*)(wq + (ct * 16 + ll) * 64 + 32 + hl * 8);
    f32x4 a = zero4(); a = MFMA(xa0, b0, a); a = MFMA(xa1, b1, a);
#pragma unroll
    for (int r = 0; r < 4; ++r)
      qp[(w * 16 + hl * 4 + r) * 64 + ct * 16 + ll] = f2bs(elu1(a[r]));
  }

  // K = elu1(x Wk) -> kT LDS + kg global + zpart
  unsigned short* kg = kg_g + (size_t)blk * 4096;
  const unsigned short* wk = wkT + h * 4096;
#pragma unroll
  for (int ct = 0; ct < 4; ++ct) {
    bf16x8 b0 = *(const bf16x8*)(wk + (ct * 16 + ll) * 64 + hl * 8);
    bf16x8 b1 = *(const bf16x8*)(wk + (ct * 16 + ll) * 64 + 32 + hl * 8);
    f32x4 a = zero4(); a = MFMA(xa0, b0, a); a = MFMA(xa1, b1, a);
    u16x4 p; float part = 0.f;
#pragma unroll
    for (int r = 0; r < 4; ++r) {
      float kv = elu1(a[r]); part += kv;
      p[r] = f2bs(kv);
      kg[(w * 16 + hl * 4 + r) * 64 + ct * 16 + ll] = p[r];
    }
    *(u16x4*)&kT[ct * 16 + ll][w * 16 + hl * 4] = p;
    part += __shfl_xor(part, 16);
    part += __shfl_xor(part, 32);
    if (hl == 0) zpart[w][ct * 16 + ll] = part;
  }
  // V = x Wv -> vT[o][t]
  const unsigned short* wv = wvT + h * 4096;
#pragma unroll
  for (int ct = 0; ct < 4; ++ct) {
    bf16x8 b0 = *(const bf16x8*)(wv + (ct * 16 + ll) * 64 + hl * 8);
    bf16x8 b1 = *(const bf16x8*)(wv + (ct * 16 + ll) * 64 + 32 + hl * 8);
    f32x4 a = zero4(); a = MFMA(xa0, b0, a); a = MFMA(xa1, b1, a);
    u16x4 p;
#pragma unroll
    for (int r = 0; r < 4; ++r) p[r] = f2bs(a[r]);
    *(u16x4*)&vT[ct * 16 + ll][w * 16 + hl * 4] = p;
  }
  __syncthreads();

  // KtV: C[e][o]; write transposed [o][e] to mir
  const bf16x8 ka0 = *(const bf16x8*)&kT[w * 16 + ll][hl * 8];
  const bf16x8 ka1 = *(const bf16x8*)&kT[w * 16 + ll][32 + hl * 8];
  unsigned short* mp = mir + (size_t)blk * 4096;
#pragma unroll
  for (int ct = 0; ct < 4; ++ct) {
    bf16x8 v0 = *(const bf16x8*)&vT[ct * 16 + ll][hl * 8];
    bf16x8 v1 = *(const bf16x8*)&vT[ct * 16 + ll][32 + hl * 8];
    f32x4 s = zero4(); s = MFMA(ka0, v0, s); s = MFMA(ka1, v1, s);
    u16x4 p;
#pragma unroll
    for (int r = 0; r < 4; ++r) p[r] = f2bs(s[r]);
    *(u16x4*)&mp[(ct * 16 + ll) * 64 + w * 16 + hl * 4] = p;
  }
  // coalesced publish of vT
  unsigned short* vg = vtg + (size_t)blk * 4096;
#pragma unroll
  for (int it = 0; it < 2; ++it) {
    int j = tid * 8 + it * 2048;
    int r = j >> 6, col = j & 63;
    *(uint4*)&vg[j] = *(const uint4*)&vT[r][col];
  }
  if (tid < 64)
    zmir[(size_t)blk * 64 + tid] = f2bs(
        zpart[0][tid] + zpart[1][tid] + zpart[2][tid] + zpart[3][tid]);
}

// ---------------------------------------------------------------------------
// K2: exclusive prefix over chunks — loads up-front, register scan, stores.
// ---------------------------------------------------------------------------
__global__ __launch_bounds__(256) void k_prefix(
    unsigned short* __restrict__ mir, unsigned short* __restrict__ zmir)
{
  const int bh = blockIdx.x / 17, g = blockIdx.x % 17;
  const int tid = threadIdx.x;
  if (g < 16) {
    size_t base = (size_t)bh * 64 * 4096 + g * 256 + tid;
    unsigned short v[64];
#pragma unroll
    for (int cc = 0; cc < 64; ++cc) v[cc] = mir[base + (size_t)cc * 4096];
    float carry = 0.f;
#pragma unroll
    for (int cc = 0; cc < 64; ++cc) {
      float f = b2f(v[cc]);
      v[cc] = f2bs(carry);
      carry += f;
    }
#pragma unroll
    for (int cc = 0; cc < 64; ++cc) mir[base + (size_t)cc * 4096] = v[cc];
  } else if (tid < 64) {
    size_t base = (size_t)bh * 64 * 64 + tid;
    unsigned short v[64];
#pragma unroll
    for (int cc = 0; cc < 64; ++cc) v[cc] = zmir[base + (size_t)cc * 64];
    float carry = 0.f;
#pragma unroll
    for (int cc = 0; cc < 64; ++cc) {
      float f = b2f(v[cc]);
      v[cc] = f2bs(carry);
      carry += f;
    }
#pragma unroll
    for (int cc = 0; cc < 64; ++cc) zmir[base + (size_t)cc * 64] = v[cc];
  }
}

// ---------------------------------------------------------------------------
// K3: per (b,h,chunk) — ONE head per block:
//   y_h = (Q Sprev + tril(Q K^T) V) / (q.zprev + rowsum + eps)
// y_h (bf16) is written IN PLACE into this block's qg tile (each tile is
// consumed by exactly this block; each wave touches only its own 16-row
// stripe; stores depend on the MFMA results that consumed Q -> no hazard).
// Zero barriers, zero cross-block writes.
// ---------------------------------------------------------------------------
__global__ __launch_bounds__(256) void k_out_y(
    unsigned short* __restrict__ qg, const unsigned short* __restrict__ kg_g,
    const unsigned short* __restrict__ vtg, const unsigned short* __restrict__ mir,
    const unsigned short* __restrict__ zmir)
{
  __shared__ __align__(16) unsigned short ts[64][72];

  const int tid = threadIdx.x;
  const size_t sblk = blockIdx.x;
  const int lane = tid & 63, w = tid >> 6;
  const int ll = lane & 15, hl = lane >> 4;

  // Q fragments (precomputed, A-operand row layout)
  unsigned short* qp = qg + sblk * 4096;
  const bf16x8 qa0 = *(const bf16x8*)(qp + (w * 16 + ll) * 64 + hl * 8);
  const bf16x8 qa1 = *(const bf16x8*)(qp + (w * 16 + ll) * 64 + 32 + hl * 8);

  // den0 = q . zprev (this lane covers e in {hl*8..+7} u {32+hl*8..+7};
  // xor-reduce over hl groups -> full dot for row w*16+ll at every lane)
  const unsigned short* zp = zmir + sblk * 64;
  u16x8 zz0 = *(const u16x8*)(zp + hl * 8);
  u16x8 zz1 = *(const u16x8*)(zp + 32 + hl * 8);
  const u16x8 qu0 = *(const u16x8*)&qa0;
  const u16x8 qu1 = *(const u16x8*)&qa1;
  float den0 = 0.f;
#pragma unroll
  for (int i = 0; i < 8; ++i) {
    den0 += b2f(qu0[i]) * b2f(zz0[i]);
    den0 += b2f(qu1[i]) * b2f(zz1[i]);
  }
  den0 += __shfl_xor(den0, 16);
  den0 += __shfl_xor(den0, 32);

  // A = tril(Q K^T)  (K fragments from global)
  const unsigned short* kg = kg_g + sblk * 4096;
  f32x4 aacc[4];
#pragma unroll
  for (int ct = 0; ct < 4; ++ct) {
    if (ct <= w) {   // wave-uniform
      bf16x8 b0 = *(const bf16x8*)(kg + (ct * 16 + ll) * 64 + hl * 8);
      bf16x8 b1 = *(const bf16x8*)(kg + (ct * 16 + ll) * 64 + 32 + hl * 8);
      f32x4 a = zero4(); a = MFMA(qa0, b0, a); a = MFMA(qa1, b1, a);
      if (ct == w) {  // causal mask on diagonal tile (static indices)
#pragma unroll
        for (int r = 0; r < 4; ++r)
          if (ll > hl * 4 + r) a[r] = 0.f;
      }
      aacc[ct] = a;
    } else {
      aacc[ct] = zero4();
    }
  }
  // rowsum(A) for C/D rows w*16+hl*4+r
  float denA[4];
#pragma unroll
  for (int r = 0; r < 4; ++r)
    denA[r] = aacc[0][r] + aacc[1][r] + aacc[2][r] + aacc[3][r];
#pragma unroll
  for (int m = 1; m <= 8; m <<= 1)
#pragma unroll
    for (int r = 0; r < 4; ++r) denA[r] += __shfl_xor(denA[r], m);
  // den0 for row w*16+hl*4+r lives at lane (hl*4+r)
  float inv[4];
#pragma unroll
  for (int r = 0; r < 4; ++r)
    inv[r] = 1.f / (__shfl(den0, hl * 4 + r) + denA[r] + 1e-6f);

  // A transpose via ts (wave-private rows; in-order DS pipe -> safe)
#pragma unroll
  for (int ct = 0; ct < 4; ++ct)
#pragma unroll
    for (int r = 0; r < 4; ++r)
      ts[w * 16 + hl * 4 + r][ct * 16 + ll] = f2bs(aacc[ct][r]);
  const bf16x8 aa0 = *(const bf16x8*)&ts[w * 16 + ll][hl * 8];
  const bf16x8 aa1 = *(const bf16x8*)&ts[w * 16 + ll][32 + hl * 8];

  // num = Q Sprev + A V  (Sprev^T, V^T fragments from global)
  const unsigned short* sp = mir + sblk * 4096;
  const unsigned short* vg = vtg + sblk * 4096;
  f32x4 nacc[4];
#pragma unroll
  for (int ct = 0; ct < 4; ++ct) {
    bf16x8 s0 = *(const bf16x8*)(sp + (ct * 16 + ll) * 64 + hl * 8);
    bf16x8 s1 = *(const bf16x8*)(sp + (ct * 16 + ll) * 64 + 32 + hl * 8);
    f32x4 a = zero4(); a = MFMA(qa0, s0, a); a = MFMA(qa1, s1, a);
    bf16x8 v0 = *(const bf16x8*)(vg + (ct * 16 + ll) * 64 + hl * 8);
    a = MFMA(aa0, v0, a);
    if (w >= 2) {    // rows t>=32: s in [32,64) can be nonzero
      bf16x8 v1 = *(const bf16x8*)(vg + (ct * 16 + ll) * 64 + 32 + hl * 8);
      a = MFMA(aa1, v1, a);
    }
    nacc[ct] = a;
  }

  // y = num * inv  -> IN PLACE into qg tile (wave's own rows only)
#pragma unroll
  for (int ct = 0; ct < 4; ++ct)
#pragma unroll
    for (int r = 0; r < 4; ++r)
      qp[(w * 16 + hl * 4 + r) * 64 + ct * 16 + ll] =
          f2bs(nacc[ct][r] * inv[r]);
}

// ---------------------------------------------------------------------------
// K4: out[t][o2] = sum_h y_h[t][:] @ Wp_h   (y tiles live in qg)
// per (b,chunk); LDS-free, barrier-free.
// ---------------------------------------------------------------------------
__global__ __launch_bounds__(256) void k_proj(
    const unsigned short* __restrict__ qg, const unsigned short* __restrict__ wpT,
    float* __restrict__ out)
{
  const int tid = threadIdx.x, bid = blockIdx.x;
  const int c = bid & 63, b = bid >> 6;
  const int lane = tid & 63, w = tid >> 6;
  const int ll = lane & 15, hl = lane >> 4;

  f32x4 acc[4] = {zero4(), zero4(), zero4(), zero4()};
#pragma unroll 1
  for (int h = 0; h < 16; ++h) {
    const unsigned short* yp =
        qg + ((size_t)((b * 16 + h) * 64 + c)) * 4096 + (w * 16 + ll) * 64;
    bf16x8 a0 = *(const bf16x8*)(yp + hl * 8);
    bf16x8 a1 = *(const bf16x8*)(yp + 32 + hl * 8);
#pragma unroll
    for (int ct = 0; ct < 4; ++ct) {
      const unsigned short* wpr = wpT + (size_t)(ct * 16 + ll) * 1024 + h * 64;
      bf16x8 w0 = *(const bf16x8*)(wpr + hl * 8);
      bf16x8 w1 = *(const bf16x8*)(wpr + 32 + hl * 8);
      acc[ct] = MFMA(a0, w0, acc[ct]);
      acc[ct] = MFMA(a1, w1, acc[ct]);
    }
  }
  float* op = out + ((size_t)(b * Sv + c * 64)) * 64;
#pragma unroll
  for (int ct = 0; ct < 4; ++ct)
#pragma unroll
    for (int r = 0; r < 4; ++r)
      op[(size_t)(w * 16 + hl * 4 + r) * 64 + ct * 16 + ll] = acc[ct][r];
}

// ---------------------------------------------------------------------------
extern "C" void kernel_launch(void* const* d_in, const int* in_sizes, int n_in,
                              void* d_out, int out_size, void* d_ws, size_t ws_size,
                              hipStream_t stream)
{
  const float* x  = (const float*)d_in[0];
  const float* Wq = (const float*)d_in[1];
  const float* Wk = (const float*)d_in[2];
  const float* Wv = (const float*)d_in[3];
  const float* Wp = (const float*)d_in[4];
  float* out = (float*)d_out;

  // ws layout (bytes) — total 135,266,304 (== round-0's proven footprint):
  //   mir  bf16 [4096][4096]  33.55 MB
  //   kg   bf16 [4096][4096]  33.55 MB
  //   vg   bf16 [4096][4096]  33.55 MB
  //   qg   bf16 [4096][4096]  33.55 MB  (Q, overwritten in-place by y)
  //   wqT/wkT/wvT/wpT bf16    0.52 MB
  //   zmir bf16 [4096][64]    0.52 MB
  unsigned short* mir = (unsigned short*)d_ws;
  unsigned short* kg  = mir + 16777216;
  unsigned short* vg  = kg + 16777216;
  unsigned short* qg  = vg + 16777216;
  unsigned short* wqT = qg + 16777216;
  unsigned short* wkT = wqT + 65536;
  unsigned short* wvT = wkT + 65536;
  unsigned short* wpT = wvT + 65536;
  unsigned short* zmir = wpT + 65536;

  hipLaunchKernelGGL(k_prep_w, dim3(80), dim3(256), 0, stream,
                     Wq, Wk, Wv, Wp, wqT, wkT, wvT, wpT);
  hipLaunchKernelGGL(k_chunk_state, dim3(BHv * NCv), dim3(256), 0, stream,
                     x, wqT, wkT, wvT, mir, zmir, qg, kg, vg);
  hipLaunchKernelGGL(k_prefix, dim3(BHv * 17), dim3(256), 0, stream, mir, zmir);
  hipLaunchKernelGGL(k_out_y, dim3(BHv * NCv), dim3(256), 0, stream,
                     qg, kg, vg, mir, zmir);
  hipLaunchKernelGGL(k_proj, dim3(Bv * NCv), dim3(256), 0, stream,
                     qg, wpT, out);
}